// Round 19
// baseline (45.755 us; speedup 1.0000x reference)
//
#include <hip/hip_runtime.h>
#include <math.h>

#define TOKENS 16384
#define DIM 2048
#define NE 8
#define BLOCK 512              // 8 waves; 64 KB LDS -> TWO blocks co-resident per CU
#define GRID 512               // 512 blocks x 32 tokens = 16384

// DPP cross-lane (VALU pipe, not DS)
template <int CTRL>
__device__ __forceinline__ float dpp_mov(float v) {
    return __int_as_float(__builtin_amdgcn_update_dpp(
        0, __float_as_int(v), CTRL, 0xf, 0xf, true));
}
#define DPP_XOR1 0xB1   // quad_perm [1,0,3,2]
#define DPP_XOR2 0x4E   // quad_perm [2,3,0,1]

// async global->LDS, 16B/lane: per-lane global src, wave-uniform LDS dest (+lane*16)
__device__ __forceinline__ void stage16(const float* g, float* l) {
    __builtin_amdgcn_global_load_lds(
        (const __attribute__((address_space(1))) void*)g,
        (__attribute__((address_space(3))) void*)l, 16, 0, 0);
}

// chunk k (0..7): quarter q=k>>1 in buffer (q&1); j=k&1 within quarter
#define FMA_BODY(XBUF, K)                                                     \
    {                                                                         \
        const int kk = (K);                                                   \
        const int fb = ((kk >> 1) & 1) * 2048 + (kk & 1) * 64;                \
        _Pragma("unroll")                                                     \
        for (int r = 0; r < 16; ++r) {                                        \
            const float4 w = wl4[fb + r * 128 + lane];                        \
            _Pragma("unroll")                                                 \
            for (int t = 0; t < 4; ++t) {                                     \
                float a = V[r * 4 + t];                                       \
                a = fmaf(XBUF[t].x, w.x, a);                                  \
                a = fmaf(XBUF[t].y, w.y, a);                                  \
                a = fmaf(XBUF[t].z, w.z, a);                                  \
                a = fmaf(XBUF[t].w, w.w, a);                                  \
                V[r * 4 + t] = a;                                             \
            }                                                                 \
        }                                                                     \
    }
#define REFILL(XBUF, K)                                                       \
    {                                                                         \
        const int kk = (K);                                                   \
        _Pragma("unroll")                                                     \
        for (int t = 0; t < 4; ++t)                                           \
            XBUF[t] = x4[(t0 + t) * (DIM / 4) + kk * 64 + lane];              \
    }
// stage quarter q into its buffer: wave stages its gate row (wv) + noise row (wv+8)
#define STAGE_Q(Q)                                                            \
    {                                                                         \
        const int q = (Q);                                                    \
        float* dst = wlds + (q & 1) * 8192;                                   \
        _Pragma("unroll")                                                     \
        for (int i = 0; i < 2; ++i) {                                         \
            stage16(w_g + wv * DIM + q * 512 + i * 256 + lane * 4,            \
                    dst + wv * 512 + i * 256);                                \
            stage16(w_noise + wv * DIM + q * 512 + i * 256 + lane * 4,        \
                    dst + (wv + 8) * 512 + i * 256);                          \
        }                                                                     \
    }

__launch_bounds__(BLOCK, 4)   // full-unroll shape; demand ~111 VGPR, must stay <=128
__global__ void router_kernel(const float* __restrict__ x,
                              const float* __restrict__ w_g,
                              const float* __restrict__ w_noise,
                              const float* __restrict__ eps,
                              float* __restrict__ out)
{
    // two 32 KB quarter-tiles: [buf][16 rows][512 cols] = 64 KB total
    __shared__ float wlds[2 * 16 * 512];

    const int tid  = threadIdx.x;
    const int lane = tid & 63;
    const int wv   = tid >> 6;                  // 0..7
    const int t0   = (blockIdx.x * 8 + wv) * 4; // this wave's 4 tokens
    const int off  = wv & 1;                    // convoy phase within each quarter

    const float4* x4  = (const float4*)x;
    const float4* wl4 = (const float4*)wlds;

    // ---- issue Q0 staging + first x loads (latency overlaps) ----
    STAGE_Q(0);
    float4 xvA[4], xvB[4];
    REFILL(xvA, off);            // chunk a0 = 0+off
    REFILL(xvB, 1 - off);        // chunk b0 = 1-off

    float my_eps = 0.f;
    if (lane < 32) my_eps = eps[t0 * NE + lane];

    float V[64];                 // V[r*4+t]
    #pragma unroll
    for (int v = 0; v < 64; ++v) V[v] = 0.f;

    __syncthreads();             // Q0 resident (vmcnt drained by barrier)

    STAGE_Q(1);                  // in flight during Q0 compute
    FMA_BODY(xvA, off);          REFILL(xvA, 2 + off);
    FMA_BODY(xvB, 1 - off);      REFILL(xvB, 3 - off);
    __syncthreads();             // Q1 resident; all waves done reading buf0

    STAGE_Q(2);                  // overwrites buf0, safe after barrier
    FMA_BODY(xvA, 2 + off);      REFILL(xvA, 4 + off);
    FMA_BODY(xvB, 3 - off);      REFILL(xvB, 5 - off);
    __syncthreads();             // Q2 resident; done reading buf1

    STAGE_Q(3);                  // overwrites buf1
    FMA_BODY(xvA, 4 + off);      REFILL(xvA, 6 + off);
    FMA_BODY(xvB, 5 - off);      REFILL(xvB, 7 - off);
    __syncthreads();             // Q3 resident; done reading buf0

    FMA_BODY(xvA, 6 + off);
    FMA_BODY(xvB, 7 - off);

    // ---- pack-halving reduction (R17 mix): DPP stages 0,1; shfl 2..5 ----
    #pragma unroll
    for (int j = 0; j < 32; ++j) {
        const float A = V[2 * j], B = V[2 * j + 1];
        const float As = dpp_mov<DPP_XOR1>(A);
        const float Bs = dpp_mov<DPP_XOR1>(B);
        V[j] = (lane & 1) ? (B + Bs) : (A + As);
    }
    #pragma unroll
    for (int j = 0; j < 16; ++j) {
        const float A = V[2 * j], B = V[2 * j + 1];
        const float As = dpp_mov<DPP_XOR2>(A);
        const float Bs = dpp_mov<DPP_XOR2>(B);
        V[j] = (lane & 2) ? (B + Bs) : (A + As);
    }
    #pragma unroll
    for (int s = 2; s < 6; ++s) {
        const int m = 1 << s;
        const int n = 64 >> s;
        #pragma unroll
        for (int j = 0; j < n / 2; ++j) {
            const float A = V[2 * j], B = V[2 * j + 1];
            const float As = __shfl_xor(A, m, 64);
            const float Bs = __shfl_xor(B, m, 64);
            V[j] = (lane & m) ? (B + Bs) : (A + As);
        }
    }
    const float mine = V[0];            // lane L: row (L>>2), token t0+(L&3)

    const float other = __shfl_xor(mine, 32, 64);

    if (lane < 32) {
        const int e = lane >> 2;
        const int t = lane & 3;
        const int tok = t0 + t;

        const float ev = __shfl(my_eps, (t << 3) | e, 64);

        const float nv = other;
        const float sp = fmaxf(nv, 0.f) + log1pf(expf(-fabsf(nv)));  // stable softplus
        const float logit = fmaf(sp, ev, mine);

        // top-2 across the 8 lanes sharing token t (e lives in lane bits 2..4)
        float v1 = logit, v2 = -INFINITY;
        int   i1 = e,     i2 = 7;
        #pragma unroll
        for (int sm = 2; sm <= 4; ++sm) {
            const int m = 1 << sm;
            const float ov1 = __shfl_xor(v1, m, 64);
            const float ov2 = __shfl_xor(v2, m, 64);
            const int   oi1 = __shfl_xor(i1, m, 64);
            const int   oi2 = __shfl_xor(i2, m, 64);
            const bool firstA = (v1 > ov1) || (v1 == ov1 && i1 < oi1);
            const float nv1 = firstA ? v1  : ov1;
            const int   ni1 = firstA ? i1  : oi1;
            const float ca  = firstA ? ov1 : v1;
            const int   cia = firstA ? oi1 : i1;
            const float cb  = firstA ? v2  : ov2;
            const int   cib = firstA ? i2  : oi2;
            const bool secondA = (ca > cb) || (ca == cb && cia < cib);
            v1 = nv1; i1 = ni1;
            v2 = secondA ? ca : cb;
            i2 = secondA ? cia : cib;
        }

        if (e == 0) {                   // lanes 0..3: lane == t
            *(float2*)&out[2 * tok] = make_float2(v1, v2);
            *(float2*)&out[2 * TOKENS + 2 * tok] = make_float2((float)i1, (float)i2);
        }
    }
}

extern "C" void kernel_launch(void* const* d_in, const int* in_sizes, int n_in,
                              void* d_out, int out_size, void* d_ws, size_t ws_size,
                              hipStream_t stream) {
    const float* x       = (const float*)d_in[0];
    const float* w_g     = (const float*)d_in[1];
    const float* w_noise = (const float*)d_in[2];
    const float* eps     = (const float*)d_in[3];
    float* out = (float*)d_out;

    router_kernel<<<GRID, BLOCK, 0, stream>>>(x, w_g, w_noise, eps, out);
}

// Round 21
// 36.278 us; speedup vs baseline: 1.2612x; 1.2612x over previous
//
#include <hip/hip_runtime.h>
#include <math.h>

#define TOKENS 16384
#define DIM 2048
#define NE 8
#define BLOCK 256              // 4 independent waves; NO LDS tile, NO barrier
#define GRID 1024              // 1024 blocks x 16 tokens = 16384

// DPP cross-lane (VALU pipe, not DS)
template <int CTRL>
__device__ __forceinline__ float dpp_mov(float v) {
    return __int_as_float(__builtin_amdgcn_update_dpp(
        0, __float_as_int(v), CTRL, 0xf, 0xf, true));
}
#define DPP_XOR1 0xB1   // quad_perm [1,0,3,2]
#define DPP_XOR2 0x4E   // quad_perm [2,3,0,1]
#define DPP_XOR8 0x128  // row_ror:8 == xor-8 within each 16-lane row

// weights read straight from global: 128 KB is L2-resident per XCD after first
// touch (~67 GB/s/CU demand << L2 share). Removes LDS staging + barriers + the
// DS-pipe weight reads that every 1-block/CU variant serialized on (R17-R19).
#define FMA_BODY(XBUF, KC)                                              \
    {                                                                   \
        const int kk = (KC);                                            \
        _Pragma("unroll")                                               \
        for (int r = 0; r < 8; ++r) {                                   \
            const float4 wg = g4[r * 512 + kk * 64 + lane];             \
            const float4 wn = n4[r * 512 + kk * 64 + lane];             \
            _Pragma("unroll")                                           \
            for (int t = 0; t < 4; ++t) {                               \
                float a = V[r * 4 + t];                                 \
                a = fmaf(XBUF[t].x, wg.x, a);                           \
                a = fmaf(XBUF[t].y, wg.y, a);                           \
                a = fmaf(XBUF[t].z, wg.z, a);                           \
                a = fmaf(XBUF[t].w, wg.w, a);                           \
                V[r * 4 + t] = a;                                       \
                float b = V[32 + r * 4 + t];                            \
                b = fmaf(XBUF[t].x, wn.x, b);                           \
                b = fmaf(XBUF[t].y, wn.y, b);                           \
                b = fmaf(XBUF[t].z, wn.z, b);                           \
                b = fmaf(XBUF[t].w, wn.w, b);                           \
                V[32 + r * 4 + t] = b;                                  \
            }                                                           \
        }                                                               \
    }
#define REFILL(XBUF, KC)                                                \
    {                                                                   \
        const int kk = (KC);                                            \
        _Pragma("unroll")                                               \
        for (int t = 0; t < 4; ++t)                                     \
            XBUF[t] = x4[(t0 + t) * (DIM / 4) + kk * 64 + lane];        \
    }

__launch_bounds__(BLOCK, 4)   // full-unroll shape: proven >=128-VGPR allocation
__global__ void router_kernel(const float* __restrict__ x,
                              const float* __restrict__ w_g,
                              const float* __restrict__ w_noise,
                              const float* __restrict__ eps,
                              float* __restrict__ out)
{
    const int tid  = threadIdx.x;
    const int lane = tid & 63;
    const int wv   = tid >> 6;                  // 0..3
    const int t0   = (blockIdx.x * 4 + wv) * 4; // this wave's 4 tokens
    const int off  = (wv & 3) * 2;              // mild initial desync

    const float4* x4 = (const float4*)x;
    const float4* g4 = (const float4*)w_g;      // rows: V[0..31] = gate
    const float4* n4 = (const float4*)w_noise;  // rows: V[32..63] = noise

    // x prefetch for first two scheduled chunks
    float4 xvA[4], xvB[4];
    REFILL(xvA, off);
    REFILL(xvB, (1 + off) & 7);

    // coalesced eps preload (lanes<32): eps[t0*8 .. t0*8+31]
    float my_eps = 0.f;
    if (lane < 32) my_eps = eps[t0 * NE + lane];

    // V[r*4+t] gate rows 0..7; V[32+r*4+t] noise rows 0..7
    float V[64];
    #pragma unroll
    for (int v = 0; v < 64; ++v) V[v] = 0.f;

    #pragma unroll
    for (int i = 0; i < 8; i += 2) {
        const int kA = (i + off) & 7;
        const int kB = (i + 1 + off) & 7;
        FMA_BODY(xvA, kA);
        if (i + 2 < 8) REFILL(xvA, (i + 2 + off) & 7);
        FMA_BODY(xvB, kB);
        if (i + 3 < 8) REFILL(xvB, (i + 3 + off) & 7);
    }

    // ---- pack-halving reduction: DPP stages 0,1,3; shfl 2,4,5 (R17/R18 mix) ----
    // V ordering note: value index L maps lane L -> (gate rows 0..7 for L<32,
    // noise rows for L>=32), token t0+(L&3) -- identical semantics to R17
    // because V[32..63] are the noise rows (previously rows 8..15).
    #pragma unroll
    for (int j = 0; j < 32; ++j) {
        const float A = V[2 * j], B = V[2 * j + 1];
        const float As = dpp_mov<DPP_XOR1>(A);
        const float Bs = dpp_mov<DPP_XOR1>(B);
        V[j] = (lane & 1) ? (B + Bs) : (A + As);
    }
    #pragma unroll
    for (int j = 0; j < 16; ++j) {
        const float A = V[2 * j], B = V[2 * j + 1];
        const float As = dpp_mov<DPP_XOR2>(A);
        const float Bs = dpp_mov<DPP_XOR2>(B);
        V[j] = (lane & 2) ? (B + Bs) : (A + As);
    }
    #pragma unroll
    for (int j = 0; j < 8; ++j) {
        const float A = V[2 * j], B = V[2 * j + 1];
        const float As = __shfl_xor(A, 4, 64);
        const float Bs = __shfl_xor(B, 4, 64);
        V[j] = (lane & 4) ? (B + Bs) : (A + As);
    }
    #pragma unroll
    for (int j = 0; j < 4; ++j) {
        const float A = V[2 * j], B = V[2 * j + 1];
        const float As = dpp_mov<DPP_XOR8>(A);
        const float Bs = dpp_mov<DPP_XOR8>(B);
        V[j] = (lane & 8) ? (B + Bs) : (A + As);
    }
    #pragma unroll
    for (int j = 0; j < 2; ++j) {
        const float A = V[2 * j], B = V[2 * j + 1];
        const float As = __shfl_xor(A, 16, 64);
        const float Bs = __shfl_xor(B, 16, 64);
        V[j] = (lane & 16) ? (B + Bs) : (A + As);
    }
    {
        const float A = V[0], B = V[1];
        const float As = __shfl_xor(A, 32, 64);
        const float Bs = __shfl_xor(B, 32, 64);
        V[0] = (lane & 32) ? (B + Bs) : (A + As);
    }
    const float mine = V[0];           // lane L<32: gate(e=L>>2, t=L&3); L>=32: noise

    const float other = __shfl_xor(mine, 32, 64);

    if (lane < 32) {
        const int e = lane >> 2;
        const int t = lane & 3;
        const int tok = t0 + t;

        const float ev = __shfl(my_eps, (t << 3) | e, 64);

        const float nv = other;
        const float sp = fmaxf(nv, 0.f) + log1pf(expf(-fabsf(nv)));  // stable softplus
        const float logit = fmaf(sp, ev, mine);

        // top-2 across the 8 lanes sharing token t (e lives in lane bits 2..4)
        float v1 = logit, v2 = -INFINITY;
        int   i1 = e,     i2 = 7;
        #pragma unroll
        for (int sm = 2; sm <= 4; ++sm) {
            const int m = 1 << sm;
            const float ov1 = __shfl_xor(v1, m, 64);
            const float ov2 = __shfl_xor(v2, m, 64);
            const int   oi1 = __shfl_xor(i1, m, 64);
            const int   oi2 = __shfl_xor(i2, m, 64);
            const bool firstA = (v1 > ov1) || (v1 == ov1 && i1 < oi1);
            const float nv1 = firstA ? v1  : ov1;
            const int   ni1 = firstA ? i1  : oi1;
            const float ca  = firstA ? ov1 : v1;
            const int   cia = firstA ? oi1 : i1;
            const float cb  = firstA ? v2  : ov2;
            const int   cib = firstA ? i2  : oi2;
            const bool secondA = (ca > cb) || (ca == cb && cia < cib);
            v1 = nv1; i1 = ni1;
            v2 = secondA ? ca : cb;
            i2 = secondA ? cia : cib;
        }

        if (e == 0) {                  // lanes 0..3: lane == t
            *(float2*)&out[2 * tok] = make_float2(v1, v2);
            *(float2*)&out[2 * TOKENS + 2 * tok] = make_float2((float)i1, (float)i2);
        }
    }
}

extern "C" void kernel_launch(void* const* d_in, const int* in_sizes, int n_in,
                              void* d_out, int out_size, void* d_ws, size_t ws_size,
                              hipStream_t stream) {
    const float* x       = (const float*)d_in[0];
    const float* w_g     = (const float*)d_in[1];
    const float* w_noise = (const float*)d_in[2];
    const float* eps     = (const float*)d_in[3];
    float* out = (float*)d_out;

    router_kernel<<<GRID, BLOCK, 0, stream>>>(x, w_g, w_noise, eps, out);
}

// Round 22
// 31.757 us; speedup vs baseline: 1.4408x; 1.1424x over previous
//
#include <hip/hip_runtime.h>
#include <math.h>

#define TOKENS 16384
#define DIM 2048
#define NE 8
#define BLOCK 1024             // 16 waves, 1 block/CU (128 KiB LDS)
#define GRID 256
#define NCHUNK (DIM / 256)     // 8 chunks of 64 float4

// DPP cross-lane (VALU pipe, not DS): quad_perm patterns give xor-1 / xor-2.
template <int CTRL>
__device__ __forceinline__ float dpp_xor(float v) {
    return __int_as_float(__builtin_amdgcn_update_dpp(
        0, __float_as_int(v), CTRL, 0xf, 0xf, true));
}
#define DPP_XOR1 0xB1   // quad_perm [1,0,3,2]
#define DPP_XOR2 0x4E   // quad_perm [2,3,0,1]

__launch_bounds__(BLOCK, 4)   // full-unroll shape: allocator picks >=128 VGPR (R10/R11/R16)
__global__ void router_kernel(const float* __restrict__ x,
                              const float* __restrict__ w_g,
                              const float* __restrict__ w_noise,
                              const float* __restrict__ eps,
                              float* __restrict__ out)
{
    __shared__ float wlds[16 * DIM];   // rows 0..7 = w_g, 8..15 = w_noise

    const int tid  = threadIdx.x;
    const int lane = tid & 63;
    const int wv   = tid >> 6;                   // 0..15
    const int t0   = (blockIdx.x * 16 + wv) * 4; // this wave's 4 tokens

    // convoy-breaker (R11, validated): per-wave chunk phase
    const int off  = (wv & 3) * 2;

    const float4* x4 = (const float4*)x;

    // ---- issue x loads for steps 0/1 FIRST: latency overlaps weight staging ----
    float4 xvA[4], xvB[4];
    {
        const int c0 = off;
        const int c1 = (1 + off) & 7;
        #pragma unroll
        for (int t = 0; t < 4; ++t) xvA[t] = x4[(t0 + t) * (DIM / 4) + c0 * 64 + lane];
        #pragma unroll
        for (int t = 0; t < 4; ++t) xvB[t] = x4[(t0 + t) * (DIM / 4) + c1 * 64 + lane];
    }

    // early eps (lanes<32): eps[t0*8 .. t0*8+31] for this wave's 4 tokens
    float my_eps = 0.f;
    if (lane < 32) my_eps = eps[t0 * NE + lane];

    // ---- stage weights (coalesced float4) ----
    {
        const float4* g4 = (const float4*)w_g;
        const float4* n4 = (const float4*)w_noise;
        float4* l4 = (float4*)wlds;
        #pragma unroll
        for (int i = tid; i < (NE * DIM) / 4; i += BLOCK) {
            l4[i] = g4[i];
            l4[i + (NE * DIM) / 4] = n4[i];
        }
    }
    __syncthreads();

    const float4* wl4 = (const float4*)wlds;

    // V[r*4+t]: partial dot of row r (0..15) with token t0+t
    float V[64];
    #pragma unroll
    for (int v = 0; v < 64; ++v) V[v] = 0.f;

    // ---- k-loop, chunk = (i+off)&7, unrolled x2, 2-buffer refill (R11) ----
    #pragma unroll
    for (int i = 0; i < NCHUNK; i += 2) {
        const int kA = (i + off) & 7;
        const int kB = (i + 1 + off) & 7;

        #pragma unroll
        for (int r = 0; r < 16; ++r) {
            const float4 w = wl4[r * (DIM / 4) + kA * 64 + lane];
            #pragma unroll
            for (int t = 0; t < 4; ++t) {
                float a = V[r * 4 + t];
                a = fmaf(xvA[t].x, w.x, a);
                a = fmaf(xvA[t].y, w.y, a);
                a = fmaf(xvA[t].z, w.z, a);
                a = fmaf(xvA[t].w, w.w, a);
                V[r * 4 + t] = a;
            }
        }
        if (i + 2 < NCHUNK) {
            const int kN = (i + 2 + off) & 7;
            #pragma unroll
            for (int t = 0; t < 4; ++t)
                xvA[t] = x4[(t0 + t) * (DIM / 4) + kN * 64 + lane];
        }
        #pragma unroll
        for (int r = 0; r < 16; ++r) {
            const float4 w = wl4[r * (DIM / 4) + kB * 64 + lane];
            #pragma unroll
            for (int t = 0; t < 4; ++t) {
                float a = V[r * 4 + t];
                a = fmaf(xvB[t].x, w.x, a);
                a = fmaf(xvB[t].y, w.y, a);
                a = fmaf(xvB[t].z, w.z, a);
                a = fmaf(xvB[t].w, w.w, a);
                V[r * 4 + t] = a;
            }
        }
        if (i + 3 < NCHUNK) {
            const int kN = (i + 3 + off) & 7;
            #pragma unroll
            for (int t = 0; t < 4; ++t)
                xvB[t] = x4[(t0 + t) * (DIM / 4) + kN * 64 + lane];
        }
    }

    // ---- pack-halving reduction: stages 0/1 on DPP (VALU pipe), 2..5 on shfl ----
    #pragma unroll
    for (int j = 0; j < 32; ++j) {     // stage 0: xor-1 via quad_perm
        const float A = V[2 * j];
        const float B = V[2 * j + 1];
        const float As = dpp_xor<DPP_XOR1>(A);
        const float Bs = dpp_xor<DPP_XOR1>(B);
        V[j] = (lane & 1) ? (B + Bs) : (A + As);
    }
    #pragma unroll
    for (int j = 0; j < 16; ++j) {     // stage 1: xor-2 via quad_perm
        const float A = V[2 * j];
        const float B = V[2 * j + 1];
        const float As = dpp_xor<DPP_XOR2>(A);
        const float Bs = dpp_xor<DPP_XOR2>(B);
        V[j] = (lane & 2) ? (B + Bs) : (A + As);
    }
    #pragma unroll
    for (int s = 2; s < 6; ++s) {      // stages 2..5: xor 4/8/16/32 via shfl
        const int m = 1 << s;
        const int n = 64 >> s;
        #pragma unroll
        for (int j = 0; j < n / 2; ++j) {
            const float A = V[2 * j];
            const float B = V[2 * j + 1];
            const float As = __shfl_xor(A, m, 64);
            const float Bs = __shfl_xor(B, m, 64);
            V[j] = (lane & m) ? (B + Bs) : (A + As);
        }
    }
    const float mine = V[0];            // lane L: row (L>>2), token t0+(L&3)

    // lanes <32 hold gate sums (rows 0..7); lane+32 holds matching noise sum
    const float other = __shfl_xor(mine, 32, 64);

    if (lane < 32) {
        const int e = lane >> 2;
        const int t = lane & 3;
        const int tok = t0 + t;

        // eps[t*8+e] is held by lane (t<<3)|e
        const float ev = __shfl(my_eps, (t << 3) | e, 64);

        const float nv = other;
        const float sp = fmaxf(nv, 0.f) + log1pf(expf(-fabsf(nv)));  // stable softplus
        const float logit = fmaf(sp, ev, mine);

        // top-2 across the 8 lanes sharing token t (e lives in lane bits 2..4)
        float v1 = logit, v2 = -INFINITY;
        int   i1 = e,     i2 = 7;
        #pragma unroll
        for (int sm = 2; sm <= 4; ++sm) {
            const int m = 1 << sm;
            const float ov1 = __shfl_xor(v1, m, 64);
            const float ov2 = __shfl_xor(v2, m, 64);
            const int   oi1 = __shfl_xor(i1, m, 64);
            const int   oi2 = __shfl_xor(i2, m, 64);
            // merge two (desc-value, asc-index) sorted pairs
            const bool firstA = (v1 > ov1) || (v1 == ov1 && i1 < oi1);
            const float nv1 = firstA ? v1  : ov1;
            const int   ni1 = firstA ? i1  : oi1;
            const float ca  = firstA ? ov1 : v1;    // losing head
            const int   cia = firstA ? oi1 : i1;
            const float cb  = firstA ? v2  : ov2;   // winner's second
            const int   cib = firstA ? i2  : oi2;
            const bool secondA = (ca > cb) || (ca == cb && cia < cib);
            v1 = nv1; i1 = ni1;
            v2 = secondA ? ca : cb;
            i2 = secondA ? cia : cib;
        }

        if (e == 0) {                   // lanes 0..3: lane == t
            *(float2*)&out[2 * tok] = make_float2(v1, v2);
            *(float2*)&out[2 * TOKENS + 2 * tok] = make_float2((float)i1, (float)i2);
        }
    }
}

extern "C" void kernel_launch(void* const* d_in, const int* in_sizes, int n_in,
                              void* d_out, int out_size, void* d_ws, size_t ws_size,
                              hipStream_t stream) {
    const float* x       = (const float*)d_in[0];
    const float* w_g     = (const float*)d_in[1];
    const float* w_noise = (const float*)d_in[2];
    const float* eps     = (const float*)d_in[3];
    float* out = (float*)d_out;

    router_kernel<<<GRID, BLOCK, 0, stream>>>(x, w_g, w_noise, eps, out);
}